// Round 3
// baseline (376.166 us; speedup 1.0000x reference)
//
#include <hip/hip_runtime.h>
#include <math.h>

// y = ifft2(fft2(x, ortho) * sqrt_lambda, ortho).real ; filter real+even ->
// pack two real images as z = a + i*b, out_a = Re, out_b = Im.
// 64-pt FFT = radix-8 x radix-8; ONE lane-transpose per 1-D FFT through the
// wave's own tile cells. All ortho scaling (1/4096) folded into the filter.
//
// R3 structure: persistent-ish pipeline. Grid 1024 blocks x 6 pairs each.
// Pair p+1's 16 input floats are prefetched into registers immediately after
// pair p's inputs are consumed, so global-load latency hides under pair p's
// ~20us of compute and HBM streams instead of bursting (R2 showed 35% HBM
// duty cycle with the burst structure: load-burst / compute / store-burst).
//
// LDS bank-conflict-free lane mapping (validated R1/R2: conflicts 4.5e7->3.1e6):
//   o = lane&7 is the ROW/COLUMN offset (fast digit), u = lane>>3 the FFT
//   digit -> in-order LDS batches span 8 rows (stride 33 float4, odd) ->
//   conflict-free in A/C. Phase B uses tB = rev3(u) + sub-float2 swap (q>=2)
//   so column reads/writes and scratch reads are conflict-free too.
//
// __launch_bounds__(512, 4): 2nd arg is min waves per EU -> VGPR cap 128.
// (512,8) caps at 64 VGPRs and SPILLS (R1: WRITE_SIZE = 1.5x output, +25%
// dur). Do not tighten.

__device__ __forceinline__ float2 cadd(float2 a, float2 b){ return make_float2(a.x+b.x, a.y+b.y); }
__device__ __forceinline__ float2 csub(float2 a, float2 b){ return make_float2(a.x-b.x, a.y-b.y); }
__device__ __forceinline__ float2 cmul(float2 a, float2 b){ return make_float2(a.x*b.x - a.y*b.y, a.x*b.y + a.y*b.x); }
__device__ __forceinline__ float2 cmulc(float2 a, float2 b){ // a * conj(b)
  return make_float2(a.x*b.x + a.y*b.y, a.y*b.x - a.x*b.y);
}

template<int SGN>
__device__ __forceinline__ float2 crot(float2 a){  // multiply by SGN*i
  return (SGN < 0) ? make_float2(a.y, -a.x) : make_float2(-a.y, a.x);
}

template<int SGN>
__device__ __forceinline__ void fft8(float2 a[8]){
  const float s = 0.70710678118654752440f;
  float2 e0=a[0], e1=a[2], e2=a[4], e3=a[6];
  float2 o0=a[1], o1=a[3], o2=a[5], o3=a[7];
  float2 t0=cadd(e0,e2), t1=csub(e0,e2), t2=cadd(e1,e3), t3=crot<SGN>(csub(e1,e3));
  float2 E0=cadd(t0,t2), E2=csub(t0,t2), E1=cadd(t1,t3), E3=csub(t1,t3);
  float2 u0=cadd(o0,o2), u1=csub(o0,o2), u2=cadd(o1,o3), u3=crot<SGN>(csub(o1,o3));
  float2 O0=cadd(u0,u2), O2=csub(u0,u2), O1=cadd(u1,u3), O3=csub(u1,u3);
  const float2 w1 = make_float2( s, (SGN < 0) ? -s : s);
  const float2 w3 = make_float2(-s, (SGN < 0) ? -s : s);
  O1 = cmul(O1, w1);
  O2 = crot<SGN>(O2);
  O3 = cmul(O3, w3);
  a[0]=cadd(E0,O0); a[4]=csub(E0,O0);
  a[1]=cadd(E1,O1); a[5]=csub(E1,O1);
  a[2]=cadd(E2,O2); a[6]=csub(E2,O2);
  a[3]=cadd(E3,O3); a[7]=csub(E3,O3);
}

// intra-wave LDS producer/consumer ordering pin (DS pipe is in-order per wave)
__device__ __forceinline__ void lds_sync(){
  __builtin_amdgcn_fence(__ATOMIC_ACQ_REL, "wavefront");
  __builtin_amdgcn_wave_barrier();
  __builtin_amdgcn_fence(__ATOMIC_ACQ_REL, "wavefront");
}

// tw[j] = exp(-i*2*pi*t*j/64), built as 1 sincos + 7 cmuls; rebuilt per phase
// since A/C use tA and B uses tB (keeps the live set small).
__device__ __forceinline__ void build_tw(int t, float2 tw[8]){
  float sv, cv;
  __sincosf(-(float)M_PI * (float)t / 32.0f, &sv, &cv);
  const float2 wstep = make_float2(cv, sv);
  tw[0] = make_float2(1.f, 0.f);
  #pragma unroll
  for (int j = 1; j < 8; ++j) tw[j] = cmul(tw[j-1], wstep);
}

// ---------------------------------------------------------------------------
// Kernel 1: permuted, pre-scaled sqrt(lambda). One block of 256 threads.
// Fperm[kr*64 + c] = F[kr][swap(c)], swap(8a+b)=8b+a (column digit-swap only).
// ---------------------------------------------------------------------------
__global__ void filter_kernel(const float* __restrict__ g1p,
                              const float* __restrict__ rawd,
                              const int*   __restrict__ bidx,
                              float*       __restrict__ Sperm){
  __shared__ float gsh[16];
  __shared__ float red[256];
  const int tid = threadIdx.x;
  if (tid == 0){
    float g = g1p[0];
    gsh[0] = g;
    for (int b = 0; b < 15; ++b){
      float d = rawd[b];
      float sp = (d > 20.f) ? d : log1pf(expf(d));  // softplus
      g += sp;
      gsh[b+1] = g;
    }
  }
  __syncthreads();
  float ell[16];
  float sacc = 0.f;
  #pragma unroll
  for (int i = 0; i < 16; ++i){
    int p = tid + 256*i;
    ell[i] = gsh[bidx[p]];
    sacc += ell[i];
  }
  red[tid] = sacc; __syncthreads();
  for (int off = 128; off > 0; off >>= 1){
    if (tid < off) red[tid] += red[tid + off];
    __syncthreads();
  }
  float mean1 = red[0] * (1.f/4096.f);
  __syncthreads();
  sacc = 0.f;
  #pragma unroll
  for (int i = 0; i < 16; ++i){
    float e = ell[i] - mean1;
    e = fminf(fmaxf(e, -3.f), 3.f);
    ell[i] = e;
    sacc += e;
  }
  red[tid] = sacc; __syncthreads();
  for (int off = 128; off > 0; off >>= 1){
    if (tid < off) red[tid] += red[tid + off];
    __syncthreads();
  }
  float mean2 = red[0] * (1.f/4096.f);
  #pragma unroll
  for (int i = 0; i < 16; ++i){
    int p = tid + 256*i;
    int h = p >> 6, w = p & 63;
    float val = expf(0.5f * (ell[i] - mean2)) * (1.0f/4096.0f);
    int pw = ((w & 7) << 3) | (w >> 3);      // column digit-swap only
    Sperm[h*64 + pw] = val;
  }
}

// ---------------------------------------------------------------------------
// Kernel 2: 1024 blocks x 6 image pairs each, register-prefetch pipelined.
// 512 threads, 64x66 float2 tile.
// ---------------------------------------------------------------------------
__global__ __launch_bounds__(512, 4) void spectral_kernel(
    const float* __restrict__ x, const float* __restrict__ Sp, float* __restrict__ y)
{
  __shared__ float2 tile[64*66];
  float4* tile4 = reinterpret_cast<float4*>(tile);
  const int tid = threadIdx.x;
  const int wv = tid >> 6;            // wave index 0..7
  const int l  = tid & 63;            // lane
  const int o  = l & 7;               // fast digit: row/col offset within wave's 8
  const int u  = l >> 3;              // slow digit
  const int g  = (wv << 3) + o;       // phase A/C: row
  const int tA = u;                   // phase A/C: FFT digit lane
  const int c  = (wv << 3) + o;       // phase B: column
  const int tB = ((u & 1) << 2) | (u & 2) | (u >> 2);   // rev3(u)
  const int mB = (tB < 4) ? tB : (tB ^ 1);              // sub-swapped scratch read col
  const int off = (g << 6) + tA;      // per-thread global element offset

  float2 tw[8];
  float ldA[8], ldB[8];

  // prefetch pair 0
  {
    const float* p0 = x + ((long long)blockIdx.x << 13);
    #pragma unroll
    for (int j = 0; j < 8; ++j){ ldA[j] = p0[off + 8*j]; ldB[j] = p0[off + 4096 + 8*j]; }
  }

  #pragma unroll 1
  for (int p = 0; p < 6; ++p){
    float2 a[8];
    // consume prefetched inputs (vmcnt wait lands here; loads were issued a
    // whole pair ago for p>=1)
    #pragma unroll
    for (int j = 0; j < 8; ++j) a[j] = make_float2(ldA[j], ldB[j]);

    // issue next pair's loads right away: they complete under this pair's
    // compute. Stores of pair p are issued later (younger) so the consume
    // wait above never waits on them (vmcnt retires in order).
    if (p < 5){
      const float* pn = x + ((long long)((p+1)*1024 + blockIdx.x) << 13);
      #pragma unroll
      for (int j = 0; j < 8; ++j){ ldA[j] = pn[off + 8*j]; ldB[j] = pn[off + 4096 + 8*j]; }
    }

    // ================= Phase A: forward row FFT =================
    build_tw(tA, tw);
    fft8<-1>(a);                                    // -> k2
    #pragma unroll
    for (int j = 1; j < 8; ++j) a[j] = cmul(a[j], tw[j]);   // w64^{n1*k2}
    #pragma unroll
    for (int q = 0; q < 4; ++q)
      tile4[33*g + 4*tA + q] = make_float4(a[2*q].x, a[2*q].y, a[2*q+1].x, a[2*q+1].y);
    lds_sync();
    #pragma unroll
    for (int j = 0; j < 8; ++j) a[j] = tile[66*g + 8*j + tA];   // thread=k2, regs=n1
    fft8<-1>(a);                                    // -> k1
    lds_sync();
    #pragma unroll
    for (int q = 0; q < 4; ++q)   // logical col s = 8t+j holds X[t+8j]
      tile4[33*g + 4*tA + q] = make_float4(a[2*q].x, a[2*q].y, a[2*q+1].x, a[2*q+1].y);
    __syncthreads();

    // ========== Phase B: column FFT + filter + inverse column FFT ==========
    build_tw(tB, tw);
    #pragma unroll
    for (int j = 0; j < 8; ++j) a[j] = tile[66*(tB + 8*j) + c];   // n1=tB, regs=n2
    fft8<-1>(a);                                    // -> k2
    #pragma unroll
    for (int j = 1; j < 8; ++j) a[j] = cmul(a[j], tw[j]);
    lds_sync();
    #pragma unroll
    for (int q = 0; q < 4; ++q){    // scratch = wave's own 8 columns; q>=2 sub-swapped
      float2 lo = a[2*q], hi = a[2*q+1];
      if (q >= 2){ float2 t2 = lo; lo = hi; hi = t2; }
      tile4[33*(8*tB + o) + 4*wv + q] = make_float4(lo.x, lo.y, hi.x, hi.y);
    }
    lds_sync();
    #pragma unroll
    for (int j = 0; j < 8; ++j) a[j] = tile[66*(8*j + o) + 8*wv + mB];  // thread=k2, regs=n1
    fft8<-1>(a);                                    // -> k1 ; k_row = tB + 8j
    #pragma unroll
    for (int j = 0; j < 8; ++j){
      float f = Sp[((tB + 8*j) << 6) + c];          // 16KB table, L1-resident
      a[j].x *= f; a[j].y *= f;
    }
    fft8<+1>(a);                                    // k1 -> n1
    #pragma unroll
    for (int j = 1; j < 8; ++j) a[j] = cmulc(a[j], tw[j]);   // conj(w64^{n1*k2})
    lds_sync();
    #pragma unroll
    for (int q = 0; q < 4; ++q){
      float2 lo = a[2*q], hi = a[2*q+1];
      if (q >= 2){ float2 t2 = lo; lo = hi; hi = t2; }
      tile4[33*(8*tB + o) + 4*wv + q] = make_float4(lo.x, lo.y, hi.x, hi.y);
    }
    lds_sync();
    #pragma unroll
    for (int j = 0; j < 8; ++j) a[j] = tile[66*(8*j + o) + 8*wv + mB];  // thread=n1, regs=k2
    fft8<+1>(a);                                    // -> n2
    lds_sync();
    #pragma unroll
    for (int j = 0; j < 8; ++j) tile[66*(tB + 8*j) + c] = a[j];   // spatial rows tB+8j
    __syncthreads();

    // ================= Phase C: inverse row FFT + store =================
    build_tw(tA, tw);
    #pragma unroll
    for (int q = 0; q < 4; ++q){
      float4 v = tile4[33*g + 4*tA + q];            // cols 8t+j hold k = t+8j
      a[2*q]   = make_float2(v.x, v.y);
      a[2*q+1] = make_float2(v.z, v.w);
    }
    fft8<+1>(a);                                    // k1 -> n1
    #pragma unroll
    for (int j = 1; j < 8; ++j) a[j] = cmulc(a[j], tw[j]);
    lds_sync();
    #pragma unroll
    for (int q = 0; q < 4; ++q)
      tile4[33*g + 4*tA + q] = make_float4(a[2*q].x, a[2*q].y, a[2*q+1].x, a[2*q+1].y);
    lds_sync();
    #pragma unroll
    for (int j = 0; j < 8; ++j) a[j] = tile[66*g + 8*j + tA];   // thread=n1, regs=k2
    fft8<+1>(a);                                    // -> n2 ; holds x[t + 8j]
    {
      float* py = y + ((long long)(p*1024 + blockIdx.x) << 13);
      #pragma unroll
      for (int j = 0; j < 8; ++j){
        py[off + 8*j]        = a[j].x;
        py[off + 4096 + 8*j] = a[j].y;
      }
    }
    // Phase C and next phase A touch only this wave's own 8 rows ->
    // wave-level ordering pin is sufficient (no block barrier needed here).
    lds_sync();
  }
}

extern "C" void kernel_launch(void* const* d_in, const int* in_sizes, int n_in,
                              void* d_out, int out_size, void* d_ws, size_t ws_size,
                              hipStream_t stream){
  (void)in_sizes; (void)n_in; (void)out_size; (void)ws_size;
  const float* x    = (const float*)d_in[0];
  const float* g1   = (const float*)d_in[1];
  const float* rawd = (const float*)d_in[2];
  const int*   bidx = (const int*)d_in[3];
  float* y     = (float*)d_out;
  float* Sperm = (float*)d_ws;   // 4096 floats

  filter_kernel<<<dim3(1), dim3(256), 0, stream>>>(g1, rawd, bidx, Sperm);
  spectral_kernel<<<dim3(1024), dim3(512), 0, stream>>>(x, Sperm, y);
}

// Round 4
// 366.832 us; speedup vs baseline: 1.0254x; 1.0254x over previous
//
#include <hip/hip_runtime.h>
#include <math.h>

// y = ifft2(fft2(x, ortho) * sqrt_lambda, ortho).real ; filter real+even ->
// pack two real images as z = a + i*b, out_a = Re, out_b = Im.
// 64-pt FFT = radix-8 x radix-8; ONE lane-transpose per 1-D FFT through the
// wave's own tile cells. All ortho scaling (1/4096) folded into the filter.
//
// R4 synthesis of R0-R3 evidence:
//  - Occupancy scales ~1/VGPR here (R0: 32 VGPR/76%, R2: 40/56%, R3: 52/38%)
//    and duration tracks occupancy, because each wave is a serial
//    LDS->wait->fft8 chain hidden only by TLP. So: MINIMIZE VGPRs.
//  - R0 was LDS-conflict-bound (4.5e7 conflict cycles ~= 73us/CU, LDS ~80%
//    busy). Fix conflicts WITHOUT adding registers:
//    o = lane&7 is the fast digit (row/col offset), u = lane>>3 the FFT
//    digit t, SAME t for all phases (one twiddle table, built once, 8
//    independent sincos - no per-phase rebuild chains, no second table).
//    Bank check per in-order batch (8 lanes b128 / 16 lanes b64):
//      A/C b128 ops: banks 4o+16u+4q -> 8 distinct, clean
//      A/C + scratch b64 reads: banks 4o+2u -> 16 distinct, clean
//      B scratch b128 writes: banks 4o -> 8 distinct, clean
//      B column b64 read/write: 2-way on 6/16 banks (2-way is free, m136)
//  - Grid 6144 (one pair/block): short blocks stagger naturally, which is
//    what kept R0's pipes overlapped. R3's persistent/prefetch structure
//    (phase-locked blocks, +20 VGPR) gained nothing. Reverted.
//
// __launch_bounds__(512, 4): 2nd arg is min waves per EU -> VGPR cap 128.
// (512,8) caps at 64 VGPRs and SPILLS (R1: WRITE_SIZE = 1.5x output, +25%
// dur). Do not tighten.

__device__ __forceinline__ float2 cadd(float2 a, float2 b){ return make_float2(a.x+b.x, a.y+b.y); }
__device__ __forceinline__ float2 csub(float2 a, float2 b){ return make_float2(a.x-b.x, a.y-b.y); }
__device__ __forceinline__ float2 cmul(float2 a, float2 b){ return make_float2(a.x*b.x - a.y*b.y, a.x*b.y + a.y*b.x); }
__device__ __forceinline__ float2 cmulc(float2 a, float2 b){ // a * conj(b)
  return make_float2(a.x*b.x + a.y*b.y, a.y*b.x - a.x*b.y);
}

template<int SGN>
__device__ __forceinline__ float2 crot(float2 a){  // multiply by SGN*i
  return (SGN < 0) ? make_float2(a.y, -a.x) : make_float2(-a.y, a.x);
}

template<int SGN>
__device__ __forceinline__ void fft8(float2 a[8]){
  const float s = 0.70710678118654752440f;
  float2 e0=a[0], e1=a[2], e2=a[4], e3=a[6];
  float2 o0=a[1], o1=a[3], o2=a[5], o3=a[7];
  float2 t0=cadd(e0,e2), t1=csub(e0,e2), t2=cadd(e1,e3), t3=crot<SGN>(csub(e1,e3));
  float2 E0=cadd(t0,t2), E2=csub(t0,t2), E1=cadd(t1,t3), E3=csub(t1,t3);
  float2 u0=cadd(o0,o2), u1=csub(o0,o2), u2=cadd(o1,o3), u3=crot<SGN>(csub(o1,o3));
  float2 O0=cadd(u0,u2), O2=csub(u0,u2), O1=cadd(u1,u3), O3=csub(u1,u3);
  const float2 w1 = make_float2( s, (SGN < 0) ? -s : s);
  const float2 w3 = make_float2(-s, (SGN < 0) ? -s : s);
  O1 = cmul(O1, w1);
  O2 = crot<SGN>(O2);
  O3 = cmul(O3, w3);
  a[0]=cadd(E0,O0); a[4]=csub(E0,O0);
  a[1]=cadd(E1,O1); a[5]=csub(E1,O1);
  a[2]=cadd(E2,O2); a[6]=csub(E2,O2);
  a[3]=cadd(E3,O3); a[7]=csub(E3,O3);
}

// intra-wave LDS producer/consumer ordering pin (DS pipe is in-order per wave)
__device__ __forceinline__ void lds_sync(){
  __builtin_amdgcn_fence(__ATOMIC_ACQ_REL, "wavefront");
  __builtin_amdgcn_wave_barrier();
  __builtin_amdgcn_fence(__ATOMIC_ACQ_REL, "wavefront");
}

// ---------------------------------------------------------------------------
// Kernel 1: permuted, pre-scaled sqrt(lambda). One block of 256 threads.
// Fperm[kr*64 + c] = F[kr][swap(c)], swap(8a+b)=8b+a (column digit-swap only).
// ---------------------------------------------------------------------------
__global__ void filter_kernel(const float* __restrict__ g1p,
                              const float* __restrict__ rawd,
                              const int*   __restrict__ bidx,
                              float*       __restrict__ Sperm){
  __shared__ float gsh[16];
  __shared__ float red[256];
  const int tid = threadIdx.x;
  if (tid == 0){
    float g = g1p[0];
    gsh[0] = g;
    for (int b = 0; b < 15; ++b){
      float d = rawd[b];
      float sp = (d > 20.f) ? d : log1pf(expf(d));  // softplus
      g += sp;
      gsh[b+1] = g;
    }
  }
  __syncthreads();
  float ell[16];
  float sacc = 0.f;
  #pragma unroll
  for (int i = 0; i < 16; ++i){
    int p = tid + 256*i;
    ell[i] = gsh[bidx[p]];
    sacc += ell[i];
  }
  red[tid] = sacc; __syncthreads();
  for (int off = 128; off > 0; off >>= 1){
    if (tid < off) red[tid] += red[tid + off];
    __syncthreads();
  }
  float mean1 = red[0] * (1.f/4096.f);
  __syncthreads();
  sacc = 0.f;
  #pragma unroll
  for (int i = 0; i < 16; ++i){
    float e = ell[i] - mean1;
    e = fminf(fmaxf(e, -3.f), 3.f);
    ell[i] = e;
    sacc += e;
  }
  red[tid] = sacc; __syncthreads();
  for (int off = 128; off > 0; off >>= 1){
    if (tid < off) red[tid] += red[tid + off];
    __syncthreads();
  }
  float mean2 = red[0] * (1.f/4096.f);
  #pragma unroll
  for (int i = 0; i < 16; ++i){
    int p = tid + 256*i;
    int h = p >> 6, w = p & 63;
    float val = expf(0.5f * (ell[i] - mean2)) * (1.0f/4096.0f);
    int pw = ((w & 7) << 3) | (w >> 3);      // column digit-swap only
    Sperm[h*64 + pw] = val;
  }
}

// ---------------------------------------------------------------------------
// Kernel 2: one block per image PAIR. 512 threads, 64x66 float2 tile.
// ---------------------------------------------------------------------------
__global__ __launch_bounds__(512, 4) void spectral_kernel(
    const float* __restrict__ x, const float* __restrict__ Sp, float* __restrict__ y)
{
  __shared__ float2 tile[64*66];
  float4* tile4 = reinterpret_cast<float4*>(tile);
  const int tid = threadIdx.x;
  const int wv = tid >> 6;            // wave index 0..7
  const int l  = tid & 63;            // lane
  const int o  = l & 7;               // fast digit: row/col offset within wave's 8
  const int t  = l >> 3;              // FFT digit (same for all phases)
  const int g  = (wv << 3) + o;       // row (phases A/C) and column (phase B)

  const long long baseA = (long long)blockIdx.x * 8192;
  const float* xA = x + baseA;
  const float* xB = xA + 4096;
  float* yA = y + baseA;
  float* yB = yA + 4096;

  // per-thread twiddles, built ONCE: tw[j] = exp(-i*2*pi*t*j/64);
  // symmetric, inverse = conj. 8 independent sincos (no serial chain).
  float2 tw[8];
  #pragma unroll
  for (int j = 0; j < 8; ++j){
    float sv, cv;
    __sincosf(-(float)M_PI * (float)(t*j) / 32.0f, &sv, &cv);
    tw[j] = make_float2(cv, sv);
  }

  // ================= Phase A: load + forward row FFT =================
  {
    const float* rA = xA + (g << 6);
    const float* rB = xB + (g << 6);
    float2 a[8];
    #pragma unroll
    for (int j = 0; j < 8; ++j) a[j] = make_float2(rA[t + 8*j], rB[t + 8*j]);  // n1=t, regs=n2
    fft8<-1>(a);                                    // -> k2
    #pragma unroll
    for (int j = 1; j < 8; ++j) a[j] = cmul(a[j], tw[j]);   // w64^{n1*k2}
    // transpose among the row's 8 digit-lanes via the wave's own rows
    #pragma unroll
    for (int q = 0; q < 4; ++q)
      tile4[33*g + 4*t + q] = make_float4(a[2*q].x, a[2*q].y, a[2*q+1].x, a[2*q+1].y);
    lds_sync();
    #pragma unroll
    for (int j = 0; j < 8; ++j) a[j] = tile[66*g + 8*j + t];   // thread=k2, regs=n1
    fft8<-1>(a);                                    // -> k1
    lds_sync();
    #pragma unroll
    for (int q = 0; q < 4; ++q)   // logical col s = 8t+j holds X[t+8j]
      tile4[33*g + 4*t + q] = make_float4(a[2*q].x, a[2*q].y, a[2*q+1].x, a[2*q+1].y);
  }
  __syncthreads();

  // ========== Phase B: column FFT + filter + inverse column FFT ==========
  {
    const int c = g;                  // this thread's column
    float2 a[8];
    #pragma unroll
    for (int j = 0; j < 8; ++j) a[j] = tile[66*(t + 8*j) + c];   // n1=t, regs=n2
    fft8<-1>(a);                                    // -> k2
    #pragma unroll
    for (int j = 1; j < 8; ++j) a[j] = cmul(a[j], tw[j]);
    lds_sync();
    #pragma unroll
    for (int q = 0; q < 4; ++q)     // scratch = the wave's own 8 columns
      tile4[33*(8*t + o) + 4*wv + q] = make_float4(a[2*q].x, a[2*q].y, a[2*q+1].x, a[2*q+1].y);
    lds_sync();
    #pragma unroll
    for (int j = 0; j < 8; ++j) a[j] = tile[66*(8*j + o) + 8*wv + t];  // thread=k2, regs=n1
    fft8<-1>(a);                                    // -> k1 ; k_row = t + 8j
    #pragma unroll
    for (int j = 0; j < 8; ++j){
      float f = Sp[((t + 8*j) << 6) + c];           // 16KB table, L1/L2-resident
      a[j].x *= f; a[j].y *= f;
    }
    fft8<+1>(a);                                    // k1 -> n1
    #pragma unroll
    for (int j = 1; j < 8; ++j) a[j] = cmulc(a[j], tw[j]);   // conj(w64^{n1*k2})
    lds_sync();
    #pragma unroll
    for (int q = 0; q < 4; ++q)
      tile4[33*(8*t + o) + 4*wv + q] = make_float4(a[2*q].x, a[2*q].y, a[2*q+1].x, a[2*q+1].y);
    lds_sync();
    #pragma unroll
    for (int j = 0; j < 8; ++j) a[j] = tile[66*(8*j + o) + 8*wv + t];  // thread=n1, regs=k2
    fft8<+1>(a);                                    // -> n2
    lds_sync();
    #pragma unroll
    for (int j = 0; j < 8; ++j) tile[66*(t + 8*j) + c] = a[j];   // spatial rows t+8j
  }
  __syncthreads();

  // ================= Phase C: inverse row FFT + store =================
  {
    float2 a[8];
    #pragma unroll
    for (int q = 0; q < 4; ++q){
      float4 v = tile4[33*g + 4*t + q];             // cols 8t+j hold k = t+8j
      a[2*q]   = make_float2(v.x, v.y);
      a[2*q+1] = make_float2(v.z, v.w);
    }
    fft8<+1>(a);                                    // k1 -> n1
    #pragma unroll
    for (int j = 1; j < 8; ++j) a[j] = cmulc(a[j], tw[j]);
    lds_sync();
    #pragma unroll
    for (int q = 0; q < 4; ++q)
      tile4[33*g + 4*t + q] = make_float4(a[2*q].x, a[2*q].y, a[2*q+1].x, a[2*q+1].y);
    lds_sync();
    #pragma unroll
    for (int j = 0; j < 8; ++j) a[j] = tile[66*g + 8*j + t];   // thread=n1, regs=k2
    fft8<+1>(a);                                    // -> n2 ; holds x[t + 8j]
    float* pA = yA + (g << 6) + t;
    float* pB = yB + (g << 6) + t;
    #pragma unroll
    for (int j = 0; j < 8; ++j){ pA[8*j] = a[j].x; pB[8*j] = a[j].y; }
  }
}

extern "C" void kernel_launch(void* const* d_in, const int* in_sizes, int n_in,
                              void* d_out, int out_size, void* d_ws, size_t ws_size,
                              hipStream_t stream){
  (void)in_sizes; (void)n_in; (void)out_size; (void)ws_size;
  const float* x    = (const float*)d_in[0];
  const float* g1   = (const float*)d_in[1];
  const float* rawd = (const float*)d_in[2];
  const int*   bidx = (const int*)d_in[3];
  float* y     = (float*)d_out;
  float* Sperm = (float*)d_ws;   // 4096 floats

  filter_kernel<<<dim3(1), dim3(256), 0, stream>>>(g1, rawd, bidx, Sperm);
  spectral_kernel<<<dim3(6144), dim3(512), 0, stream>>>(x, Sperm, y);
}